// Round 12
// baseline (92.554 us; speedup 1.0000x reference)
//
#include <hip/hip_runtime.h>
#include <stdint.h>

#define K_DIM 4096
#define N_DIM 11008
#define M_DIM 256

typedef uint32_t u32;
using frag_ab = __attribute__((ext_vector_type(8))) short;   // 8 bf16
using frag_cd = __attribute__((ext_vector_type(4))) float;   // 4 f32

__device__ __forceinline__ u32 f2bf_rn(float f) {
    u32 u = __builtin_bit_cast(u32, f);
    return (u + 0x7FFFu + ((u >> 16) & 1u)) >> 16;   // round-to-nearest-even
}
__device__ __forceinline__ float bf2f(u32 b) {
    return __builtin_bit_cast(float, b << 16);
}

// bf16(32+v) = 0x4200 | (v<<2).  For packed byte q = hi<<4|lo:
// q*0x4004 = q<<14 | q<<2 (no carries); mask -> {32+lo, 32+hi} bf16x2.
#define BFCVT(q) ((u32)((__mul24((int)(q), 0x4004) & 0x003C003C) | 0x42004200))

// Kernel 1: rowsum[m] = sum_k round_bf16(x[m][k])  (so the +32 trick's
// rank-1 correction cancels exactly).
__global__ __launch_bounds__(256) void rowsum_kernel(const float* __restrict__ x,
                                                     float* __restrict__ rowsum) {
    const int row = blockIdx.x;
    const int tid = threadIdx.x;
    const float* xr = x + (size_t)row * K_DIM;
    float s = 0.0f;
#pragma unroll
    for (int p = 0; p < 4; ++p) {
        int i = p * 1024 + tid * 4;
        float4 v = *reinterpret_cast<const float4*>(xr + i);
        s += bf2f(f2bf_rn(v.x)) + bf2f(f2bf_rn(v.y)) +
             bf2f(f2bf_rn(v.z)) + bf2f(f2bf_rn(v.w));
    }
#pragma unroll
    for (int off = 32; off > 0; off >>= 1) s += __shfl_down(s, off, 64);
    __shared__ float wsum[4];
    if ((tid & 63) == 0) wsum[tid >> 6] = s;
    __syncthreads();
    if (tid == 0) rowsum[row] = wsum[0] + wsum[1] + wsum[2] + wsum[3];
}

// Kernel 2: build A' = x rounded to bf16, in MFMA-fragment-major layout:
// uint4 index ((mq*128 + s)*4 + mf)*64 + c*16 + l4 holds
// A[m = mq*64+mf*16+l4][k = s*32 + c*8 .. +7].  One wave-instruction in the
// GEMM then loads a full fragment with a single coalesced dwordx4.
__global__ __launch_bounds__(256) void permute_kernel(const float* __restrict__ x,
                                                      uint4* __restrict__ abuf) {
    const int bx = blockIdx.x;
    const int mb = bx >> 4, kb = bx & 15;
    const int tid = threadIdx.x;
    const int g = tid >> 6, c = (tid >> 4) & 3, r = tid & 15;
    const int mq = mb >> 2, mf = mb & 3;
    const float* src0 = x + (size_t)(mb * 16 + r) * K_DIM;
#pragma unroll
    for (int h = 0; h < 2; ++h) {
        int s = kb * 8 + g + 4 * h;
        const float* sp = src0 + s * 32 + c * 8;
        float4 v0 = *reinterpret_cast<const float4*>(sp);
        float4 v1 = *reinterpret_cast<const float4*>(sp + 4);
        uint4 w;
        w.x = f2bf_rn(v0.x) | (f2bf_rn(v0.y) << 16);
        w.y = f2bf_rn(v0.z) | (f2bf_rn(v0.w) << 16);
        w.z = f2bf_rn(v1.x) | (f2bf_rn(v1.y) << 16);
        w.w = f2bf_rn(v1.z) | (f2bf_rn(v1.w) << 16);
        abuf[(size_t)(((mq * 128 + s) * 4 + mf) * 64 + c * 16 + r)] = w;
    }
}

// ---- GEMM: no LDS, no barriers.  Wave tile 64m x 16n, K-half per block
// (split-K=2).  Depth-4 register pipeline of asm-volatile global loads with
// counted vmcnt(24).  launch_bounds (256,4): VGPR cap 128 >= 56 used -> NO
// spills (scratch ops would count in vmcnt and corrupt the wait discipline).

#define ISSUE(AS, QS) {                                                      \
    asm volatile("global_load_dwordx4 %0, %4, %5 offset:0\n\t"               \
                 "global_load_dwordx4 %1, %4, %5 offset:1024\n\t"            \
                 "global_load_dwordx4 %2, %4, %5 offset:2048\n\t"            \
                 "global_load_dwordx4 %3, %4, %5 offset:3072"                \
                 : "=&v"(AS[0]), "=&v"(AS[1]), "=&v"(AS[2]), "=&v"(AS[3])    \
                 : "v"(va), "s"(ap));                                        \
    asm volatile("global_load_dword %0, %4, %8\n\t"                          \
                 "global_load_dword %1, %5, %8\n\t"                          \
                 "global_load_dword %2, %6, %8\n\t"                          \
                 "global_load_dword %3, %7, %8"                              \
                 : "=&v"(QS[0]), "=&v"(QS[1]), "=&v"(QS[2]), "=&v"(QS[3])    \
                 : "v"(vb[0]), "v"(vb[1]), "v"(vb[2]), "v"(vb[3]), "s"(bp)); \
    ap += 4096; bp += (size_t)16 * N_DIM * 4; }

#define STEP(AS, QS, W) {                                                    \
    asm volatile("s_waitcnt vmcnt(" #W ")" ::: "memory");                    \
    __builtin_amdgcn_sched_barrier(0);                                       \
    union { frag_ab f; u32 u[4]; } bb;                                       \
    bb.u[0] = BFCVT(QS[0]); bb.u[1] = BFCVT(QS[1]);                          \
    bb.u[2] = BFCVT(QS[2]); bb.u[3] = BFCVT(QS[3]);                          \
    acc[0] = __builtin_amdgcn_mfma_f32_16x16x32_bf16(AS[0], bb.f, acc[0], 0, 0, 0); \
    acc[1] = __builtin_amdgcn_mfma_f32_16x16x32_bf16(AS[1], bb.f, acc[1], 0, 0, 0); \
    acc[2] = __builtin_amdgcn_mfma_f32_16x16x32_bf16(AS[2], bb.f, acc[2], 0, 0, 0); \
    acc[3] = __builtin_amdgcn_mfma_f32_16x16x32_bf16(AS[3], bb.f, acc[3], 0, 0, 0); }

__global__ __launch_bounds__(256, 4) void gemm_kernel(const int* __restrict__ qw,
                                                      const float* __restrict__ scales,
                                                      const float* __restrict__ zeroes,
                                                      const uint4* __restrict__ abuf,
                                                      const float* __restrict__ rowsum,
                                                      float* __restrict__ out,
                                                      float* __restrict__ partial,
                                                      int split2) {
    const int tid  = threadIdx.x;
    const int lane = tid & 63;
    const int wid  = tid >> 6;
    const int l4   = lane & 15;
    const int c    = lane >> 4;

    // XCD-bijective swizzle; the blocks sharing one n-tile (4 mq x 2 sp) are
    // consecutive wg -> same XCD -> B slice served from its L2.
    const int orig = blockIdx.x;
    int nb, mq, sp, NS2;
    if (split2) {
        int wg = (orig & 7) * 172 + (orig >> 3);   // 1376 = 8*172
        nb = wg >> 3; mq = (wg >> 1) & 3; sp = wg & 1; NS2 = 64;
    } else {
        int wg = (orig & 7) * 86 + (orig >> 3);    // 688 = 8*86
        nb = wg >> 2; mq = wg & 3; sp = 0; NS2 = 128;
    }
    const int m0 = mq * 64;
    const int n0 = nb * 64 + wid * 16;   // wave's 16 output cols

    const char* ap = (const char*)abuf + (size_t)mq * 524288 +
                     (size_t)sp * 262144;                       // A' slice
    const char* bp = (const char*)qw + (size_t)sp * 64 * 16 * N_DIM * 4;
    u32 va = (u32)(lane * 16);
    u32 vb[4];
#pragma unroll
    for (int p = 0; p < 4; ++p)
        vb[p] = (u32)(((c * 4 + p) * N_DIM + n0 + l4) * 4);

    frag_cd acc[4];
#pragma unroll
    for (int i = 0; i < 4; ++i) acc[i] = (frag_cd){0.f, 0.f, 0.f, 0.f};

    frag_ab A0[4], A1[4], A2[4], A3[4];
    u32 Q0[4], Q1[4], Q2[4], Q3[4];

    // prologue: fill 4-deep pipeline (32 loads in flight)
    ISSUE(A0, Q0); ISSUE(A1, Q1); ISSUE(A2, Q2); ISSUE(A3, Q3);

    // main: consume oldest set, refill 4 steps ahead.  No barriers.
    const int iters = NS2 / 4 - 1;
    for (int i = 0; i < iters; ++i) {
        STEP(A0, Q0, 24); ISSUE(A0, Q0);
        STEP(A1, Q1, 24); ISSUE(A1, Q1);
        STEP(A2, Q2, 24); ISSUE(A2, Q2);
        STEP(A3, Q3, 24); ISSUE(A3, Q3);
    }
    // tail: drain 24 -> 16 -> 8 -> 0
    STEP(A0, Q0, 24);
    STEP(A1, Q1, 16);
    STEP(A2, Q2, 8);
    STEP(A3, Q3, 0);

    // epilogue
    const float sc = scales[n0 + l4];
    if (sp == 0) {
        const float zp = zeroes[n0 + l4] + 32.0f * sc;
#pragma unroll
        for (int mf = 0; mf < 4; ++mf) {
            const float4 rs = *reinterpret_cast<const float4*>(&rowsum[m0 + mf * 16 + c * 4]);
            float* op = out + (size_t)(m0 + mf * 16 + c * 4) * N_DIM + n0 + l4;
            op[0]                  = sc * acc[mf][0] - zp * rs.x;
            op[N_DIM]              = sc * acc[mf][1] - zp * rs.y;
            op[2 * (size_t)N_DIM]  = sc * acc[mf][2] - zp * rs.z;
            op[3 * (size_t)N_DIM]  = sc * acc[mf][3] - zp * rs.w;
        }
    } else {
#pragma unroll
        for (int mf = 0; mf < 4; ++mf) {
            float* op = partial + (size_t)(m0 + mf * 16 + c * 4) * N_DIM + n0 + l4;
            op[0]                  = sc * acc[mf][0];
            op[N_DIM]              = sc * acc[mf][1];
            op[2 * (size_t)N_DIM]  = sc * acc[mf][2];
            op[3 * (size_t)N_DIM]  = sc * acc[mf][3];
        }
    }
}

// Kernel 3: out += partial.  Exact cover of 256*11008 floats:
// 2752 blocks * 256 threads * 4 floats = 2,818,048.
__global__ __launch_bounds__(256) void reduce_kernel(float* __restrict__ out,
                                                     const float* __restrict__ partial) {
    size_t i = ((size_t)blockIdx.x * 256 + threadIdx.x) * 4;
    float4 o = *reinterpret_cast<float4*>(out + i);
    float4 p = *reinterpret_cast<const float4*>(partial + i);
    o.x += p.x; o.y += p.y; o.z += p.z; o.w += p.w;
    *reinterpret_cast<float4*>(out + i) = o;
}

extern "C" void kernel_launch(void* const* d_in, const int* in_sizes, int n_in,
                              void* d_out, int out_size, void* d_ws, size_t ws_size,
                              hipStream_t stream) {
    const float* x      = (const float*)d_in[0];
    const int*   qw     = (const int*)d_in[1];
    const float* scales = (const float*)d_in[2];
    const float* zeroes = (const float*)d_in[3];
    float* out = (float*)d_out;

    const size_t ABUF_BYTES = (size_t)2 * 1024 * 1024;      // 2 MB A'
    const size_t RS_OFF     = ABUF_BYTES;                    // 1 KB rowsum
    const size_t P_OFF      = ABUF_BYTES + 4096;
    const size_t P_BYTES    = (size_t)M_DIM * N_DIM * 4;     // 11.3 MB partial

    uint4* abuf   = (uint4*)d_ws;
    float* rowsum = (float*)((char*)d_ws + RS_OFF);
    float* part   = (float*)((char*)d_ws + P_OFF);

    const bool split2 = ws_size >= P_OFF + P_BYTES;

    rowsum_kernel<<<M_DIM, 256, 0, stream>>>(x, rowsum);
    permute_kernel<<<256, 256, 0, stream>>>(x, abuf);
    if (split2) {
        gemm_kernel<<<1376, 256, 0, stream>>>(qw, scales, zeroes, abuf, rowsum,
                                              out, part, 1);
        reduce_kernel<<<(M_DIM * N_DIM) / (256 * 4), 256, 0, stream>>>(out, part);
    } else {
        gemm_kernel<<<688, 256, 0, stream>>>(qw, scales, zeroes, abuf, rowsum,
                                             out, nullptr, 0);
    }
}

// Round 13
// 59.575 us; speedup vs baseline: 1.5536x; 1.5536x over previous
//
#include <hip/hip_runtime.h>
#include <stdint.h>

#define K_DIM 4096
#define N_DIM 11008
#define M_DIM 256

typedef uint32_t u32;
using frag_ab = __attribute__((ext_vector_type(8))) short;   // 8 bf16
using frag_cd = __attribute__((ext_vector_type(4))) float;   // 4 f32
using u32x2   = __attribute__((ext_vector_type(2))) uint32_t;

__device__ __forceinline__ u32 f2bf_rn(float f) {
    u32 u = __builtin_bit_cast(u32, f);
    return (u + 0x7FFFu + ((u >> 16) & 1u)) >> 16;   // round-to-nearest-even
}
__device__ __forceinline__ float bf2f(u32 b) {
    return __builtin_bit_cast(float, b << 16);
}

// bf16(32+v) = 0x4200 | (v<<2).  For packed byte q = hi<<4|lo:
// q*0x4004 = q<<14 | q<<2 (no carries); mask -> {32+lo, 32+hi} bf16x2.
#define BFCVT(q) ((u32)((__mul24((int)(q), 0x4004) & 0x003C003C) | 0x42004200))

// Kernel 1: rowsum[m] = sum_k round_bf16(x[m][k])
__global__ __launch_bounds__(256) void rowsum_kernel(const float* __restrict__ x,
                                                     float* __restrict__ rowsum) {
    const int row = blockIdx.x;
    const int tid = threadIdx.x;
    const float* xr = x + (size_t)row * K_DIM;
    float s = 0.0f;
#pragma unroll
    for (int p = 0; p < 4; ++p) {
        int i = p * 1024 + tid * 4;
        float4 v = *reinterpret_cast<const float4*>(xr + i);
        s += bf2f(f2bf_rn(v.x)) + bf2f(f2bf_rn(v.y)) +
             bf2f(f2bf_rn(v.z)) + bf2f(f2bf_rn(v.w));
    }
#pragma unroll
    for (int off = 32; off > 0; off >>= 1) s += __shfl_down(s, off, 64);
    __shared__ float wsum[4];
    if ((tid & 63) == 0) wsum[tid >> 6] = s;
    __syncthreads();
    if (tid == 0) rowsum[row] = wsum[0] + wsum[1] + wsum[2] + wsum[3];
}

// Kernel 2: A' = bf16(x) in MFMA-fragment-major layout (verified r10-12):
// uint4 idx ((mq*128 + s)*4 + mf)*64 + c*16 + l4 holds
// A[m = mq*64+mf*16+l4][k = s*32 + c*8 .. +7].
__global__ __launch_bounds__(256) void permute_kernel(const float* __restrict__ x,
                                                      uint4* __restrict__ abuf) {
    const int bx = blockIdx.x;
    const int mb = bx >> 4, kb = bx & 15;
    const int tid = threadIdx.x;
    const int g = tid >> 6, c = (tid >> 4) & 3, r = tid & 15;
    const int mq = mb >> 2, mf = mb & 3;
    const float* src0 = x + (size_t)(mb * 16 + r) * K_DIM;
#pragma unroll
    for (int h = 0; h < 2; ++h) {
        int s = kb * 8 + g + 4 * h;
        const float* sp = src0 + s * 32 + c * 8;
        float4 v0 = *reinterpret_cast<const float4*>(sp);
        float4 v1 = *reinterpret_cast<const float4*>(sp + 4);
        uint4 w;
        w.x = f2bf_rn(v0.x) | (f2bf_rn(v0.y) << 16);
        w.y = f2bf_rn(v0.z) | (f2bf_rn(v0.w) << 16);
        w.z = f2bf_rn(v1.x) | (f2bf_rn(v1.y) << 16);
        w.w = f2bf_rn(v1.z) | (f2bf_rn(v1.w) << 16);
        abuf[(size_t)(((mq * 128 + s) * 4 + mf) * 64 + c * 16 + r)] = w;
    }
}

// ---- GEMM: wave tile 64m x 64n (16 MFMAs / 12 load-instrs per 32-k step).
// Block = 2 waves = 64m x 128n.  No LDS, no barriers.  Depth-4 register
// pipeline, counted vmcnt(36).  B col-pair trick: lane l4 loads dwordx2 at
// col n0+2*l4 -> even/odd column fragments (output-col permutation absorbed
// in the float2 store).

#define ISSUE(AS, QS) {                                                      \
    asm volatile("global_load_dwordx4 %0, %4, %5 offset:0\n\t"               \
                 "global_load_dwordx4 %1, %4, %5 offset:1024\n\t"            \
                 "global_load_dwordx4 %2, %4, %5 offset:2048\n\t"            \
                 "global_load_dwordx4 %3, %4, %5 offset:3072"                \
                 : "=&v"(AS[0]), "=&v"(AS[1]), "=&v"(AS[2]), "=&v"(AS[3])    \
                 : "v"(va), "s"(ap));                                        \
    asm volatile("global_load_dwordx2 %0, %4, %8 offset:0\n\t"               \
                 "global_load_dwordx2 %1, %5, %8 offset:0\n\t"               \
                 "global_load_dwordx2 %2, %6, %8 offset:0\n\t"               \
                 "global_load_dwordx2 %3, %7, %8 offset:0"                   \
                 : "=&v"(QS[0]), "=&v"(QS[1]), "=&v"(QS[2]), "=&v"(QS[3])    \
                 : "v"(vb[0]), "v"(vb[1]), "v"(vb[2]), "v"(vb[3]), "s"(bp)); \
    asm volatile("global_load_dwordx2 %0, %4, %8 offset:128\n\t"             \
                 "global_load_dwordx2 %1, %5, %8 offset:128\n\t"             \
                 "global_load_dwordx2 %2, %6, %8 offset:128\n\t"             \
                 "global_load_dwordx2 %3, %7, %8 offset:128"                 \
                 : "=&v"(QS[4]), "=&v"(QS[5]), "=&v"(QS[6]), "=&v"(QS[7])    \
                 : "v"(vb[0]), "v"(vb[1]), "v"(vb[2]), "v"(vb[3]), "s"(bp)); \
    ap += 4096; bp += (size_t)16 * N_DIM * 4; }

#define STEP(AS, QS, W) {                                                    \
    asm volatile("s_waitcnt vmcnt(" #W ")" ::: "memory");                    \
    __builtin_amdgcn_sched_barrier(0);                                       \
    _Pragma("unroll")                                                        \
    for (int h = 0; h < 2; ++h) {                                            \
        union { frag_ab f; u32 u[4]; } be, bo;                               \
        _Pragma("unroll")                                                    \
        for (int p = 0; p < 4; ++p) {                                        \
            be.u[p] = BFCVT(QS[h * 4 + p][0]);                               \
            bo.u[p] = BFCVT(QS[h * 4 + p][1]);                               \
        }                                                                    \
        _Pragma("unroll")                                                    \
        for (int mf = 0; mf < 4; ++mf) {                                     \
            acc[mf][h * 2 + 0] = __builtin_amdgcn_mfma_f32_16x16x32_bf16(    \
                AS[mf], be.f, acc[mf][h * 2 + 0], 0, 0, 0);                  \
            acc[mf][h * 2 + 1] = __builtin_amdgcn_mfma_f32_16x16x32_bf16(    \
                AS[mf], bo.f, acc[mf][h * 2 + 1], 0, 0, 0);                  \
        }                                                                    \
    } }

__global__ __launch_bounds__(128, 2) void gemm_kernel(const int* __restrict__ qw,
                                                      const float* __restrict__ scales,
                                                      const float* __restrict__ zeroes,
                                                      const uint4* __restrict__ abuf,
                                                      const float* __restrict__ rowsum,
                                                      float* __restrict__ out,
                                                      float* __restrict__ partial,
                                                      int split2) {
    const int tid  = threadIdx.x;
    const int lane = tid & 63;
    const int wid  = tid >> 6;          // 0..1 (n-half of the block)
    const int l4   = lane & 15;
    const int c    = lane >> 4;

    // XCD-bijective swizzle; the 4 mq-blocks sharing one (nb,sp) B-slice are
    // consecutive wg -> same XCD L2.
    const int orig = blockIdx.x;
    int nb, mq, sp, NS2;
    if (split2) {
        int wg = (orig & 7) * 86 + (orig >> 3);    // 688 = 8*86
        nb = wg >> 3;
        int rem = wg & 7;
        sp = rem >> 2; mq = rem & 3; NS2 = 64;
    } else {
        int wg = (orig & 7) * 43 + (orig >> 3);    // 344 = 8*43
        nb = wg >> 2; mq = wg & 3; sp = 0; NS2 = 128;
    }
    const int m0  = mq * 64;
    const int n0w = nb * 128 + wid * 64;   // wave's 64 output cols

    const char* ap = (const char*)abuf + (size_t)mq * 524288 +
                     (size_t)sp * 262144;
    const char* bp = (const char*)qw + (size_t)sp * 1024 * N_DIM * 4;
    u32 va = (u32)(lane * 16);
    u32 vb[4];
#pragma unroll
    for (int p = 0; p < 4; ++p)
        vb[p] = (u32)(((c * 4 + p) * N_DIM + n0w + 2 * l4) * 4);

    frag_cd acc[4][4];   // [mf][h*2 + parity]
#pragma unroll
    for (int i = 0; i < 4; ++i)
#pragma unroll
        for (int j = 0; j < 4; ++j)
            acc[i][j] = (frag_cd){0.f, 0.f, 0.f, 0.f};

    frag_ab A0[4], A1[4], A2[4], A3[4];
    u32x2 Q0[8], Q1[8], Q2[8], Q3[8];

    // prologue: fill 4-deep pipeline (48 loads in flight)
    ISSUE(A0, Q0); ISSUE(A1, Q1); ISSUE(A2, Q2); ISSUE(A3, Q3);

    const int iters = NS2 / 4 - 1;
    for (int i = 0; i < iters; ++i) {
        STEP(A0, Q0, 36); ISSUE(A0, Q0);
        STEP(A1, Q1, 36); ISSUE(A1, Q1);
        STEP(A2, Q2, 36); ISSUE(A2, Q2);
        STEP(A3, Q3, 36); ISSUE(A3, Q3);
    }
    // tail: drain 36 -> 24 -> 12 -> 0
    STEP(A0, Q0, 36);
    STEP(A1, Q1, 24);
    STEP(A2, Q2, 12);
    STEP(A3, Q3, 0);

    // epilogue: float2 stores; col_even = n0w + h*32 + 2*l4
    if (sp == 0) {
#pragma unroll
        for (int h = 0; h < 2; ++h) {
            int ce = n0w + h * 32 + 2 * l4;
            float2 scv = *reinterpret_cast<const float2*>(&scales[ce]);
            float2 zv  = *reinterpret_cast<const float2*>(&zeroes[ce]);
            float zpx = zv.x + 32.0f * scv.x;
            float zpy = zv.y + 32.0f * scv.y;
#pragma unroll
            for (int mf = 0; mf < 4; ++mf) {
                const float4 rs = *reinterpret_cast<const float4*>(
                    &rowsum[m0 + mf * 16 + c * 4]);
                const float rsa[4] = {rs.x, rs.y, rs.z, rs.w};
#pragma unroll
                for (int j = 0; j < 4; ++j) {
                    float2 o;
                    o.x = scv.x * acc[mf][h * 2 + 0][j] - zpx * rsa[j];
                    o.y = scv.y * acc[mf][h * 2 + 1][j] - zpy * rsa[j];
                    *reinterpret_cast<float2*>(
                        &out[(size_t)(m0 + mf * 16 + c * 4 + j) * N_DIM + ce]) = o;
                }
            }
        }
    } else {
#pragma unroll
        for (int h = 0; h < 2; ++h) {
            int ce = n0w + h * 32 + 2 * l4;
            float2 scv = *reinterpret_cast<const float2*>(&scales[ce]);
#pragma unroll
            for (int mf = 0; mf < 4; ++mf) {
#pragma unroll
                for (int j = 0; j < 4; ++j) {
                    float2 o;
                    o.x = scv.x * acc[mf][h * 2 + 0][j];
                    o.y = scv.y * acc[mf][h * 2 + 1][j];
                    *reinterpret_cast<float2*>(
                        &partial[(size_t)(m0 + mf * 16 + c * 4 + j) * N_DIM + ce]) = o;
                }
            }
        }
    }
}

// Kernel 3: out += partial (exact cover: 2752 * 256 * 4 = 2,818,048 floats)
__global__ __launch_bounds__(256) void reduce_kernel(float* __restrict__ out,
                                                     const float* __restrict__ partial) {
    size_t i = ((size_t)blockIdx.x * 256 + threadIdx.x) * 4;
    float4 o = *reinterpret_cast<float4*>(out + i);
    float4 p = *reinterpret_cast<const float4*>(partial + i);
    o.x += p.x; o.y += p.y; o.z += p.z; o.w += p.w;
    *reinterpret_cast<float4*>(out + i) = o;
}

extern "C" void kernel_launch(void* const* d_in, const int* in_sizes, int n_in,
                              void* d_out, int out_size, void* d_ws, size_t ws_size,
                              hipStream_t stream) {
    const float* x      = (const float*)d_in[0];
    const int*   qw     = (const int*)d_in[1];
    const float* scales = (const float*)d_in[2];
    const float* zeroes = (const float*)d_in[3];
    float* out = (float*)d_out;

    const size_t ABUF_BYTES = (size_t)2 * 1024 * 1024;      // 2 MB A'
    const size_t RS_OFF     = ABUF_BYTES;                    // 1 KB rowsum
    const size_t P_OFF      = ABUF_BYTES + 4096;
    const size_t P_BYTES    = (size_t)M_DIM * N_DIM * 4;     // 11.3 MB partial

    uint4* abuf   = (uint4*)d_ws;
    float* rowsum = (float*)((char*)d_ws + RS_OFF);
    float* part   = (float*)((char*)d_ws + P_OFF);

    const bool split2 = ws_size >= P_OFF + P_BYTES;

    rowsum_kernel<<<M_DIM, 256, 0, stream>>>(x, rowsum);
    permute_kernel<<<256, 256, 0, stream>>>(x, abuf);
    if (split2) {
        gemm_kernel<<<688, 128, 0, stream>>>(qw, scales, zeroes, abuf, rowsum,
                                             out, part, 1);
        reduce_kernel<<<(M_DIM * N_DIM) / (256 * 4), 256, 0, stream>>>(out, part);
    } else {
        gemm_kernel<<<344, 128, 0, stream>>>(qw, scales, zeroes, abuf, rowsum,
                                             out, nullptr, 0);
    }
}

// Round 14
// 53.007 us; speedup vs baseline: 1.7461x; 1.1239x over previous
//
#include <hip/hip_runtime.h>
#include <stdint.h>

#define K_DIM 4096
#define N_DIM 11008
#define M_DIM 256

typedef uint32_t u32;
using frag_ab = __attribute__((ext_vector_type(8))) short;   // 8 bf16
using frag_cd = __attribute__((ext_vector_type(4))) float;   // 4 f32

typedef __attribute__((address_space(3))) const char lds_cc;

#define DSR128(dst, addr, off)                                       \
    asm volatile("ds_read_b128 %0, %1 offset:" #off                  \
                 : "=&v"(dst) : "v"(addr))
#define DSR32(dst, addr, off)                                        \
    asm volatile("ds_read_b32 %0, %1 offset:" #off                   \
                 : "=&v"(dst) : "v"(addr))

__device__ __forceinline__ u32 f2bf_rn(float f) {
    u32 u = __builtin_bit_cast(u32, f);
    return (u + 0x7FFFu + ((u >> 16) & 1u)) >> 16;   // round-to-nearest-even
}
__device__ __forceinline__ float bf2f(u32 b) {
    return __builtin_bit_cast(float, b << 16);
}
__device__ __forceinline__ void gll16(const void* g, void* l) {
    __builtin_amdgcn_global_load_lds(
        (const __attribute__((address_space(1))) u32*)g,
        (__attribute__((address_space(3))) u32*)l, 16, 0, 0);
}

// bf16(32+v) = 0x4200 | (v<<2); q*0x4004 = q<<14|q<<2 -> packed bf16x2.
#define BFCVT(q) ((u32)((__mul24((int)(q), 0x4004) & 0x003C003C) | 0x42004200))

// Kernel 1: x f32 -> bf16 (RN) + per-row sums of the ROUNDED values.
__global__ __launch_bounds__(256) void prep_kernel(const float* __restrict__ x,
                                                   ushort* __restrict__ xbf,
                                                   float* __restrict__ rowsum) {
    const int row = blockIdx.x;
    const int tid = threadIdx.x;
    const float* xr = x + (size_t)row * K_DIM;
    ushort* br = xbf + (size_t)row * K_DIM;
    float s = 0.0f;
#pragma unroll
    for (int p = 0; p < 4; ++p) {
        int i = p * 1024 + tid * 4;
        float4 v = *reinterpret_cast<const float4*>(xr + i);
        u32 b0 = f2bf_rn(v.x), b1 = f2bf_rn(v.y), b2 = f2bf_rn(v.z), b3 = f2bf_rn(v.w);
        uint2 o;
        o.x = b0 | (b1 << 16);
        o.y = b2 | (b3 << 16);
        *reinterpret_cast<uint2*>(br + i) = o;
        s += bf2f(b0) + bf2f(b1) + bf2f(b2) + bf2f(b3);
    }
#pragma unroll
    for (int off = 32; off > 0; off >>= 1) s += __shfl_down(s, off, 64);
    __shared__ float wsum[4];
    if ((tid & 63) == 0) wsum[tid >> 6] = s;
    __syncthreads();
    if (tid == 0) rowsum[row] = wsum[0] + wsum[1] + wsum[2] + wsum[3];
}

// Kernel 2: BM=256 (B read ONCE from HBM), BN=128, BK=32, split-K=4.
// 512 threads = 8 waves (4m x 2n), wave tile 64x64.  Triple-buffered LDS
// (72 KB -> 2 blocks/CU), gll16 staging, counted vmcnt(6/3/0), 2 barriers
// per tile, inline-asm LDS reads.  Traffic: A 172 MB + B 90 MB = 262 MB.
__global__ __launch_bounds__(512, 4) void gemm_kernel(const int* __restrict__ qw,
                                                      const float* __restrict__ scales,
                                                      const float* __restrict__ zeroes,
                                                      const ushort* __restrict__ xbf,
                                                      const float* __restrict__ rowsum,
                                                      float* __restrict__ out,
                                                      ushort* __restrict__ partial,
                                                      int split4) {
    // A tile: [m 0..255][chunk 0..3 of 16B], stored chunk' = chunk ^ ((m>>1)&3)
    // B tile: [row 0..15][col 0..127] dwords, stored col' = col ^ (((row>>2)&1)<<4)
    __shared__ uint4 Alds[3][1024];   // 3 x 16 KB
    __shared__ u32   Blds[3][2048];   // 3 x  8 KB

    const u32* qwu = (const u32*)qw;
    const int tid  = threadIdx.x;
    const int lane = tid & 63;
    const int wid  = tid >> 6;          // 0..7
    const int l4   = lane & 15;
    const int c    = lane >> 4;

    // XCD-bijective swizzle (344 = 8*43): the 4 sp-blocks of one n-strip are
    // consecutive wg -> same XCD L2 for the B slice.
    const int orig = blockIdx.x;
    int nb, sp, NTt, kb;
    if (split4) {
        int wg = (orig & 7) * 43 + (orig >> 3);
        nb = wg >> 2; sp = wg & 3; NTt = 32; kb = sp * 32;
    } else {
        nb = orig; sp = 0; NTt = 128; kb = 0;
    }
    const int n0 = nb * 128;
    const int wm = wid >> 1;            // 0..3
    const int wn = wid & 1;             // 0..1

    // ---- staging sources (pre-swizzled: linear LDS dest = swizzled layout)
    // A round j: thread covers m = (wid*2+j)*16 + (lane>>2),
    //            global chunk = (lane&3) ^ ((lane>>3)&3)   [r8-verified]
    const ushort* asrc[2];
#pragma unroll
    for (int j = 0; j < 2; ++j)
        asrc[j] = xbf + (size_t)((wid * 2 + j) * 16 + (lane >> 2)) * K_DIM +
                  8 * ((lane & 3) ^ ((lane >> 3) & 3));
    // B: thread covers row = wid*2 + (lane>>5), swz key = (wid>>1)&1
    const u32* bsrc = qwu + (size_t)(wid * 2 + (lane >> 5)) * N_DIM + n0 +
                      (((lane & 31) * 4) ^ (((wid >> 1) & 1) << 4));

    // ---- LDS read byte-offsets
    const u32 aoff = (u32)((wm * 64 + l4) * 64 + ((c ^ ((l4 >> 1) & 3)) << 4));
    const u32 b0off = (u32)((c * 512 + wn * 64 + ((c & 1) << 4) + l4) * 4);
    const u32 b1off = (u32)((c * 512 + wn * 64 + ((1 ^ (c & 1)) << 4) + l4) * 4);

    frag_cd acc[4][4];
#pragma unroll
    for (int i = 0; i < 4; ++i)
#pragma unroll
        for (int j = 0; j < 4; ++j)
            acc[i][j] = (frag_cd){0.f, 0.f, 0.f, 0.f};

    auto stage = [&](int t, int buf) {     // 3 gll16 per thread
#pragma unroll
        for (int j = 0; j < 2; ++j)
            gll16(asrc[j] + (size_t)(kb + t) * 32, &Alds[buf][(wid * 2 + j) * 64]);
        gll16(bsrc + (size_t)(kb + t) * 16 * N_DIM, &Blds[buf][wid * 256]);
    };

    auto compute = [&](int buf) {
        lds_cc* Ab = (lds_cc*)&Alds[buf][0];
        lds_cc* Bb = (lds_cc*)&Blds[buf][0];
        frag_ab afr[4];
        DSR128(afr[0], Ab + aoff, 0);
        DSR128(afr[1], Ab + aoff, 1024);
        DSR128(afr[2], Ab + aoff, 2048);
        DSR128(afr[3], Ab + aoff, 3072);
        u32 bq[16];   // [nf][p]: nf even -> b0off, odd -> b1off; imm = (nf>>1)*128 + p*512
        DSR32(bq[0],  Bb + b0off, 0);
        DSR32(bq[1],  Bb + b0off, 512);
        DSR32(bq[2],  Bb + b0off, 1024);
        DSR32(bq[3],  Bb + b0off, 1536);
        DSR32(bq[4],  Bb + b1off, 0);
        DSR32(bq[5],  Bb + b1off, 512);
        DSR32(bq[6],  Bb + b1off, 1024);
        DSR32(bq[7],  Bb + b1off, 1536);
        DSR32(bq[8],  Bb + b0off, 128);
        DSR32(bq[9],  Bb + b0off, 640);
        DSR32(bq[10], Bb + b0off, 1152);
        DSR32(bq[11], Bb + b0off, 1664);
        DSR32(bq[12], Bb + b1off, 128);
        DSR32(bq[13], Bb + b1off, 640);
        DSR32(bq[14], Bb + b1off, 1152);
        DSR32(bq[15], Bb + b1off, 1664);
        asm volatile("s_waitcnt lgkmcnt(0)" ::: "memory");
        __builtin_amdgcn_sched_barrier(0);   // rule #18
#pragma unroll
        for (int nf = 0; nf < 4; ++nf) {
            union { frag_ab f; u32 u[4]; } bb;
            bb.u[0] = BFCVT(bq[nf * 4 + 0]);
            bb.u[1] = BFCVT(bq[nf * 4 + 1]);
            bb.u[2] = BFCVT(bq[nf * 4 + 2]);
            bb.u[3] = BFCVT(bq[nf * 4 + 3]);
#pragma unroll
            for (int mf = 0; mf < 4; ++mf)
                acc[mf][nf] = __builtin_amdgcn_mfma_f32_16x16x32_bf16(
                    afr[mf], bb.f, acc[mf][nf], 0, 0, 0);
        }
    };

    // prologue: 2-deep prefetch
    stage(0, 0);
    stage(1, 1);

    int cur = 0;
    for (int t = 0; t < NTt; ++t) {
        int pbuf = cur + 2; if (pbuf >= 3) pbuf -= 3;
        if (t + 2 < NTt) {
            stage(t + 2, pbuf);
            asm volatile("s_waitcnt vmcnt(6)" ::: "memory");   // tile t landed
        } else if (t + 1 < NTt) {
            asm volatile("s_waitcnt vmcnt(3)" ::: "memory");
        } else {
            asm volatile("s_waitcnt vmcnt(0)" ::: "memory");
        }
        __builtin_amdgcn_s_barrier();
        __builtin_amdgcn_sched_barrier(0);
        compute(cur);
        asm volatile("" ::: "memory");
        __builtin_amdgcn_s_barrier();        // protect buf reuse (3-buf, 2-deep)
        ++cur; if (cur >= 3) cur -= 3;
    }

    // epilogue: logical frag (nf) maps to cols n0 + wn*64 + nf*16 + l4
    float sc[4], zp[4];
#pragma unroll
    for (int nf = 0; nf < 4; ++nf) {
        int n = n0 + wn * 64 + nf * 16 + l4;
        sc[nf] = scales[n];
        zp[nf] = zeroes[n] + 32.0f * sc[nf];
    }
    if (sp == 0) {
        float rs[4][4];
#pragma unroll
        for (int mf = 0; mf < 4; ++mf)
#pragma unroll
            for (int j = 0; j < 4; ++j)
                rs[mf][j] = rowsum[wm * 64 + mf * 16 + c * 4 + j];
#pragma unroll
        for (int mf = 0; mf < 4; ++mf)
#pragma unroll
            for (int nf = 0; nf < 4; ++nf)
#pragma unroll
                for (int j = 0; j < 4; ++j) {
                    int m = wm * 64 + mf * 16 + c * 4 + j;
                    out[(size_t)m * N_DIM + n0 + wn * 64 + nf * 16 + l4] =
                        sc[nf] * acc[mf][nf][j] - zp[nf] * rs[mf][j];
                }
    } else {
        ushort* pb = partial + (size_t)(sp - 1) * M_DIM * N_DIM;
#pragma unroll
        for (int mf = 0; mf < 4; ++mf)
#pragma unroll
            for (int nf = 0; nf < 4; ++nf)
#pragma unroll
                for (int j = 0; j < 4; ++j) {
                    int m = wm * 64 + mf * 16 + c * 4 + j;
                    pb[(size_t)m * N_DIM + n0 + wn * 64 + nf * 16 + l4] =
                        (ushort)f2bf_rn(sc[nf] * acc[mf][nf][j]);
                }
    }
}

// Kernel 3: out += bf16-partials p0+p1+p2.  Exact cover: 2752 blocks.
__global__ __launch_bounds__(256) void reduce_kernel(float* __restrict__ out,
                                                     const ushort* __restrict__ partial) {
    const size_t NTOT = (size_t)M_DIM * N_DIM;
    size_t i = ((size_t)blockIdx.x * 256 + threadIdx.x) * 4;
    float4 o = *reinterpret_cast<float4*>(out + i);
    ushort4 a = *reinterpret_cast<const ushort4*>(partial + i);
    ushort4 b = *reinterpret_cast<const ushort4*>(partial + NTOT + i);
    ushort4 d = *reinterpret_cast<const ushort4*>(partial + 2 * NTOT + i);
    o.x += bf2f(a.x) + bf2f(b.x) + bf2f(d.x);
    o.y += bf2f(a.y) + bf2f(b.y) + bf2f(d.y);
    o.z += bf2f(a.z) + bf2f(b.z) + bf2f(d.z);
    o.w += bf2f(a.w) + bf2f(b.w) + bf2f(d.w);
    *reinterpret_cast<float4*>(out + i) = o;
}

extern "C" void kernel_launch(void* const* d_in, const int* in_sizes, int n_in,
                              void* d_out, int out_size, void* d_ws, size_t ws_size,
                              hipStream_t stream) {
    const float* x      = (const float*)d_in[0];
    const int*   qw     = (const int*)d_in[1];
    const float* scales = (const float*)d_in[2];
    const float* zeroes = (const float*)d_in[3];
    float* out = (float*)d_out;

    const size_t XBF_BYTES = (size_t)M_DIM * K_DIM * 2;        // 2 MB
    const size_t RS_OFF    = XBF_BYTES;                         // 1 KB
    const size_t P_OFF     = XBF_BYTES + 4096;
    const size_t P_BYTES   = (size_t)3 * M_DIM * N_DIM * 2;     // 16.9 MB bf16

    ushort* xbf    = (ushort*)d_ws;
    float*  rowsum = (float*)((char*)d_ws + RS_OFF);
    ushort* part   = (ushort*)((char*)d_ws + P_OFF);

    const bool split4 = ws_size >= P_OFF + P_BYTES;

    prep_kernel<<<M_DIM, 256, 0, stream>>>(x, xbf, rowsum);
    if (split4) {
        gemm_kernel<<<344, 512, 0, stream>>>(qw, scales, zeroes, xbf, rowsum,
                                             out, part, 1);
        reduce_kernel<<<(M_DIM * N_DIM) / (256 * 4), 256, 0, stream>>>(out, part);
    } else {
        gemm_kernel<<<86, 512, 0, stream>>>(qw, scales, zeroes, xbf, rowsum,
                                            out, nullptr, 0);
    }
}